// Round 1
// baseline (1094.733 us; speedup 1.0000x reference)
//
#include <hip/hip_runtime.h>
#include <stdint.h>

#define EPS 1e-5f
#define SLOPE 0.01f

typedef short bf16x8 __attribute__((ext_vector_type(8)));
typedef float f32x4 __attribute__((ext_vector_type(4)));

// round-to-nearest-even fp32 -> bf16
__device__ __forceinline__ uint16_t f2bf(float x) {
  union { float f; uint32_t u; } v; v.f = x;
  return (uint16_t)((v.u + 0x7fffu + ((v.u >> 16) & 1u)) >> 16);
}

// async global->LDS, 16B per lane; LDS dest = wave-uniform base + lane*16
__device__ __forceinline__ void g2lds16(const void* g, void* l) {
  __builtin_amdgcn_global_load_lds(
      (const __attribute__((address_space(1))) void*)g,
      (__attribute__((address_space(3))) void*)l, 16, 0, 0);
}

// ---------------------------------------------------------------------------
// prep: bn scale/bias folding.  s = g/sqrt(v+eps), beta = b - m*s.
// For the point-MLP bn, bo1 is folded in: beta_o = bo + (bo1 - mo)*s.
// ---------------------------------------------------------------------------
__global__ void prep_bn(const float* g1, const float* b1, const float* m1, const float* v1,
                        const float* g2, const float* b2, const float* m2, const float* v2,
                        const float* g3, const float* b3, const float* m3, const float* v3,
                        const float* go, const float* bo, const float* mo, const float* vo,
                        const float* bo1,
                        float* s1, float* be1, float* s2, float* be2,
                        float* s3, float* be3, float* so, float* beo) {
  int t = threadIdx.x;
  if (t < 256) { float s = g1[t] / sqrtf(v1[t] + EPS); s1[t] = s; be1[t] = b1[t] - m1[t] * s; }
  if (t < 64)  { float s = g2[t] / sqrtf(v2[t] + EPS); s2[t] = s; be2[t] = b2[t] - m2[t] * s; }
  if (t < 32)  { float s = g3[t] / sqrtf(v3[t] + EPS); s3[t] = s; be3[t] = b3[t] - m3[t] * s; }
  if (t < 32)  { float s = go[t] / sqrtf(vo[t] + EPS); so[t] = s; beo[t] = bo[t] + (bo1[t] - mo[t]) * s; }
}

// ---------------------------------------------------------------------------
// weight transform: W[co][ci][27] fp32 -> Wt[t][co][ci] bf16
// ---------------------------------------------------------------------------
__global__ void wtrans(const float* __restrict__ W, uint16_t* __restrict__ Wt,
                       int CO, int CI) {
  int idx = blockIdx.x * 256 + threadIdx.x;
  int total = CO * CI * 27;
  if (idx >= total) return;
  int t = idx / (CO * CI);
  int rem = idx % (CO * CI);
  int co = rem / CI, ci = rem % CI;
  Wt[idx] = f2bf(W[((size_t)co * CI + ci) * 27 + t]);
}

// ---------------------------------------------------------------------------
// fea NCDHW fp32 -> pad0 NDHWC bf16, padded dims [66][66][18][256], halo pre-zeroed.
// One block per (b,d,h) w-row; LDS transpose for coalesced 16B writes.
// ---------------------------------------------------------------------------
__global__ __launch_bounds__(256) void transpose_fea(const float* __restrict__ fea,
                                                     uint16_t* __restrict__ pad0) {
  __shared__ __align__(16) uint16_t lds[16 * 264];  // [w][ci], stride 264 breaks bank conflicts
  int tid = threadIdx.x;
  int idx = blockIdx.x;
  int b = idx >> 12;
  int rem = idx & 4095;
  int d = rem >> 6, h = rem & 63;
  int w = tid & 15, cib = tid >> 4;
  size_t sbase = (size_t)((d * 64 + h) * 16 + w);
#pragma unroll
  for (int p = 0; p < 16; ++p) {
    int ci = p * 16 + cib;
    float v = fea[(size_t)(b * 256 + ci) * 65536 + sbase];
    lds[w * 264 + ci] = f2bf(v);
  }
  __syncthreads();
#pragma unroll
  for (int p = 0; p < 2; ++p) {
    int linear = p * 256 + tid;
    int ww = linear >> 5, c8 = linear & 31;
    uint4 val = *(const uint4*)&lds[ww * 264 + c8 * 8];
    size_t o = ((size_t)b * 78408 + (size_t)((d + 1) * 1188 + (h + 1) * 18 + (ww + 1))) * 256 + c8 * 8;
    *(uint4*)&pad0[o] = val;
  }
}

// ---------------------------------------------------------------------------
// Implicit-GEMM 3x3x3 conv, NDHWC padded bf16 in, mfma_f32_16x16x32_bf16,
// fused BN+LeakyReLU epilogue. MTILE=128 (8 h-rows x 16 w), BK=64.
// m97 2-barrier K-loop with width-16 global_load_lds staging.
// XOR swizzle: 16B unit stored at (unit ^ (row%8)) to make frag ds_read_b128
// conflict-free.
// ---------------------------------------------------------------------------
template <int CI, int CO, int NTILE, int WM, int WN, bool LAST>
__global__ __launch_bounds__(256) void conv_mfma(const uint16_t* __restrict__ padIn,
                                                 const uint16_t* __restrict__ Wt,
                                                 const float* __restrict__ bnS,
                                                 const float* __restrict__ bnB,
                                                 uint16_t* __restrict__ padOut,
                                                 float* __restrict__ x3out) {
  constexpr int MPW = 128 / WM;       // m extent per wave
  constexpr int NPW = NTILE / WN;     // n extent per wave
  constexpr int MSUB = MPW / 16;
  constexpr int NSUB = NPW / 16;
  constexpr int BPASS = NTILE / 32;   // B staging passes (32 rows per pass)
  constexpr int KC = CI / 64;

  __shared__ __align__(16) uint16_t Alds[128 * 64];     // [m][k], swizzled
  __shared__ __align__(16) uint16_t Blds[NTILE * 64];   // [n][k], swizzled

  const int tid = threadIdx.x;
  const int lane = tid & 63;
  const int wv = tid >> 6;
  const int wvm = wv / WN;
  const int wvn = wv % WN;

  const int mt = blockIdx.x;
  const int b = mt >> 9;
  const int r = mt & 511;
  const int d = r >> 3;
  const int h0 = (r & 7) << 3;
  const int n0 = blockIdx.y * NTILE;

  // staging thread constants (linear = p*256 + tid; row = linear/8; unit = linear%8)
  const int subsw = (tid & 7) ^ ((tid >> 3) & 7);  // swizzled 16B-unit
  const int wA = (tid >> 3) & 15;                  // w coordinate of A row
  const int mhA = tid >> 7;                        // h-row base (pass adds 2)
  const int rowB0 = tid >> 3;                      // B row base (pass adds 32)

  f32x4 acc[MSUB][NSUB] = {};

  const size_t bOffIn = (size_t)b * 78408 * CI;

  for (int t = 0; t < 27; ++t) {
    const int kd = t / 9, kh = (t / 3) % 3, kw = t % 3;
    const size_t Abase = bOffIn + (size_t)((d + kd) * 1188 + (h0 + kh) * 18 + kw) * CI;
    const size_t Bbase = (size_t)(t * CO + n0) * CI;
    for (int kc = 0; kc < KC; ++kc) {
      __syncthreads();  // previous iteration's LDS reads done
      {
        const uint16_t* ag = padIn + Abase + kc * 64 + (size_t)wA * CI + subsw * 8;
#pragma unroll
        for (int p = 0; p < 4; ++p)
          g2lds16(ag + (size_t)(mhA + 2 * p) * (18 * CI), (char*)Alds + p * 4096 + wv * 1024);
      }
      {
        const uint16_t* bg = Wt + Bbase + kc * 64 + subsw * 8;
#pragma unroll
        for (int p = 0; p < BPASS; ++p)
          g2lds16(bg + (size_t)(rowB0 + 32 * p) * CI, (char*)Blds + p * 4096 + wv * 1024);
      }
      __syncthreads();  // staging DMA drained (vmcnt(0) before s_barrier)
#pragma unroll
      for (int ks = 0; ks < 2; ++ks) {
        bf16x8 af[MSUB], bfr[NSUB];
#pragma unroll
        for (int mi = 0; mi < MSUB; ++mi) {
          int row = wvm * MPW + mi * 16 + (lane & 15);
          int u = (ks * 4 + (lane >> 4)) ^ (row & 7);
          af[mi] = *(const bf16x8*)&Alds[row * 64 + u * 8];
        }
#pragma unroll
        for (int ni = 0; ni < NSUB; ++ni) {
          int row = wvn * NPW + ni * 16 + (lane & 15);
          int u = (ks * 4 + (lane >> 4)) ^ (row & 7);
          bfr[ni] = *(const bf16x8*)&Blds[row * 64 + u * 8];
        }
#pragma unroll
        for (int mi = 0; mi < MSUB; ++mi)
#pragma unroll
          for (int ni = 0; ni < NSUB; ++ni)
            acc[mi][ni] = __builtin_amdgcn_mfma_f32_16x16x32_bf16(af[mi], bfr[ni], acc[mi][ni], 0, 0, 0);
      }
    }
  }

  // epilogue: y = x*s + beta, LeakyReLU; C/D layout col=lane&15, row=quad*4+r
  const int col = lane & 15;
  const int quad = lane >> 4;
#pragma unroll
  for (int ni = 0; ni < NSUB; ++ni) {
    const int co = n0 + wvn * NPW + ni * 16 + col;
    const float sv = bnS[co];
    const float bv = bnB[co];
#pragma unroll
    for (int mi = 0; mi < MSUB; ++mi) {
#pragma unroll
      for (int rr = 0; rr < 4; ++rr) {
        int m = wvm * MPW + mi * 16 + quad * 4 + rr;
        float v = acc[mi][ni][rr] * sv + bv;
        v = v > 0.f ? v : SLOPE * v;
        int mh = m >> 4, w = m & 15;
        if (!LAST) {
          size_t o = ((size_t)b * 78408 +
                      (size_t)((d + 1) * 1188 + (h0 + mh + 1) * 18 + (w + 1))) * CO + co;
          padOut[o] = f2bf(v);
        } else {
          size_t o = ((size_t)b * 65536 + (size_t)((d * 64 + h0 + mh) * 16 + w)) * 32 + co;
          x3out[o] = v;
        }
      }
    }
  }
}

// ---------------------------------------------------------------------------
// gather + point MLP, all fp32. One thread per point.
// ---------------------------------------------------------------------------
__global__ __launch_bounds__(256) void gather_mlp(const float* __restrict__ x3,
                                                  const int* __restrict__ gidx,
                                                  const float* __restrict__ xyz,
                                                  const float* __restrict__ Wo1,
                                                  const float* __restrict__ so,
                                                  const float* __restrict__ beo,
                                                  const float* __restrict__ Wo2,
                                                  const float* __restrict__ bo2,
                                                  float* __restrict__ out) {
  __shared__ __align__(16) float w1[35 * 32];
  __shared__ float w2[32 * 3];
  __shared__ float sS[32], sB[32], b2s[3];
  int tid = threadIdx.x;
  for (int i = tid; i < 1120; i += 256) w1[i] = Wo1[i];
  if (tid < 96) w2[tid] = Wo2[tid];
  if (tid < 32) { sS[tid] = so[tid]; sB[tid] = beo[tid]; }
  if (tid < 3) b2s[tid] = bo2[tid];
  __syncthreads();

  int idx = blockIdx.x * 256 + tid;
  if (idx >= 200000) return;
  int b = idx >= 100000 ? 1 : 0;
  int gb = idx * 3;
  int i0 = gidx[gb], i1 = gidx[gb + 1], i2 = gidx[gb + 2];
  const float* pt = x3 + ((size_t)b * 65536 + (size_t)((i0 * 64 + i1) * 16 + i2)) * 32;

  float h[35];
#pragma unroll
  for (int q = 0; q < 8; ++q) {
    float4 v = *(const float4*)(pt + q * 4);
    h[q * 4] = v.x; h[q * 4 + 1] = v.y; h[q * 4 + 2] = v.z; h[q * 4 + 3] = v.w;
  }
  h[32] = xyz[gb]; h[33] = xyz[gb + 1]; h[34] = xyz[gb + 2];

  float a[32];
#pragma unroll
  for (int j = 0; j < 32; ++j) a[j] = 0.f;
#pragma unroll
  for (int k = 0; k < 35; ++k) {
    float hk = h[k];
    const float4* wr = (const float4*)(w1 + k * 32);
#pragma unroll
    for (int q = 0; q < 8; ++q) {
      float4 wv = wr[q];
      a[q * 4 + 0] += hk * wv.x;
      a[q * 4 + 1] += hk * wv.y;
      a[q * 4 + 2] += hk * wv.z;
      a[q * 4 + 3] += hk * wv.w;
    }
  }
  float o0 = b2s[0], o1 = b2s[1], o2 = b2s[2];
#pragma unroll
  for (int j = 0; j < 32; ++j) {
    float y = a[j] * sS[j] + sB[j];
    y = y > 0.f ? y : 0.f;
    o0 += y * w2[j * 3 + 0];
    o1 += y * w2[j * 3 + 1];
    o2 += y * w2[j * 3 + 2];
  }
  out[gb] = o0; out[gb + 1] = o1; out[gb + 2] = o2;
}

// ---------------------------------------------------------------------------
// workspace layout (bytes):
//   pad0: 0            .. 80,289,792   (2*78408*256*2)  [later reused: pad2 @0 (20,072,448), x3 @20,072,448 (16,777,216)]
//   pad1: 80,289,792   .. 160,579,584
//   Wt1 : 160,579,584  (3,538,944)
//   Wt2 : 164,118,528  (884,736)
//   Wt3 : 165,003,264  (110,592)
//   bn  : 165,113,856  (8 slots x 1024B)
// total ~165.2 MB
// ---------------------------------------------------------------------------
extern "C" void kernel_launch(void* const* d_in, const int* in_sizes, int n_in,
                              void* d_out, int out_size, void* d_ws, size_t ws_size,
                              hipStream_t stream) {
  (void)in_sizes; (void)n_in; (void)out_size;
  if (ws_size < 165130000) return;  // workspace too small — bail loudly (absmax will fail)

  const float* fea = (const float*)d_in[0];
  const int*   gidx = (const int*)d_in[1];
  const float* xyz = (const float*)d_in[2];
  const float* W1 = (const float*)d_in[3];
  const float* g1 = (const float*)d_in[4];
  const float* b1 = (const float*)d_in[5];
  const float* m1 = (const float*)d_in[6];
  const float* v1 = (const float*)d_in[7];
  const float* W2 = (const float*)d_in[8];
  const float* g2 = (const float*)d_in[9];
  const float* b2 = (const float*)d_in[10];
  const float* m2 = (const float*)d_in[11];
  const float* v2 = (const float*)d_in[12];
  const float* W3 = (const float*)d_in[13];
  const float* g3 = (const float*)d_in[14];
  const float* b3 = (const float*)d_in[15];
  const float* m3 = (const float*)d_in[16];
  const float* v3 = (const float*)d_in[17];
  const float* Wo1 = (const float*)d_in[18];
  const float* bo1 = (const float*)d_in[19];
  const float* go = (const float*)d_in[20];
  const float* bo = (const float*)d_in[21];
  const float* mo = (const float*)d_in[22];
  const float* vo = (const float*)d_in[23];
  const float* Wo2 = (const float*)d_in[24];
  const float* bo2 = (const float*)d_in[25];

  char* ws = (char*)d_ws;
  uint16_t* pad0 = (uint16_t*)(ws);
  uint16_t* pad1 = (uint16_t*)(ws + 80289792);
  uint16_t* Wt1 = (uint16_t*)(ws + 160579584);
  uint16_t* Wt2 = (uint16_t*)(ws + 164118528);
  uint16_t* Wt3 = (uint16_t*)(ws + 165003264);
  float* s1  = (float*)(ws + 165113856 + 0 * 1024);
  float* be1 = (float*)(ws + 165113856 + 1 * 1024);
  float* s2  = (float*)(ws + 165113856 + 2 * 1024);
  float* be2 = (float*)(ws + 165113856 + 3 * 1024);
  float* s3  = (float*)(ws + 165113856 + 4 * 1024);
  float* be3 = (float*)(ws + 165113856 + 5 * 1024);
  float* so  = (float*)(ws + 165113856 + 6 * 1024);
  float* beo = (float*)(ws + 165113856 + 7 * 1024);
  // aliases into pad0's region (pad0 is dead after conv1)
  uint16_t* pad2 = (uint16_t*)(ws);
  float* x3 = (float*)(ws + 20072448);

  // zero halos of pad0+pad1 (contiguous)
  hipMemsetAsync(ws, 0, 160579584, stream);

  prep_bn<<<1, 256, 0, stream>>>(g1, b1, m1, v1, g2, b2, m2, v2, g3, b3, m3, v3,
                                 go, bo, mo, vo, bo1, s1, be1, s2, be2, s3, be3, so, beo);
  wtrans<<<6912, 256, 0, stream>>>(W1, Wt1, 256, 256);
  wtrans<<<1728, 256, 0, stream>>>(W2, Wt2, 64, 256);
  wtrans<<<216, 256, 0, stream>>>(W3, Wt3, 32, 64);
  transpose_fea<<<8192, 256, 0, stream>>>(fea, pad0);

  conv_mfma<256, 256, 128, 2, 2, false>
      <<<dim3(1024, 2), 256, 0, stream>>>(pad0, Wt1, s1, be1, pad1, nullptr);

  hipMemsetAsync(pad2, 0, 20072448, stream);  // pad2 halo (pad0 now dead; stream-ordered)

  conv_mfma<256, 64, 64, 2, 2, false>
      <<<dim3(1024, 1), 256, 0, stream>>>(pad1, Wt2, s2, be2, pad2, nullptr);

  conv_mfma<64, 32, 32, 4, 1, true>
      <<<dim3(1024, 1), 256, 0, stream>>>(pad2, Wt3, s3, be3, nullptr, x3);

  gather_mlp<<<782, 256, 0, stream>>>(x3, gidx, xyz, Wo1, so, beo, Wo2, bo2, (float*)d_out);
}

// Round 2
// 1045.878 us; speedup vs baseline: 1.0467x; 1.0467x over previous
//
#include <hip/hip_runtime.h>
#include <stdint.h>

#define EPS 1e-5f
#define SLOPE 0.01f

typedef short bf16x8 __attribute__((ext_vector_type(8)));
typedef float f32x4 __attribute__((ext_vector_type(4)));

// round-to-nearest-even fp32 -> bf16
__device__ __forceinline__ uint16_t f2bf(float x) {
  union { float f; uint32_t u; } v; v.f = x;
  return (uint16_t)((v.u + 0x7fffu + ((v.u >> 16) & 1u)) >> 16);
}

// async global->LDS, 16B per lane; LDS dest = wave-uniform base + lane*16
__device__ __forceinline__ void g2lds16(const void* g, void* l) {
  __builtin_amdgcn_global_load_lds(
      (const __attribute__((address_space(1))) void*)g,
      (__attribute__((address_space(3))) void*)l, 16, 0, 0);
}

// ---------------------------------------------------------------------------
// prep: bn scale/bias folding.  s = g/sqrt(v+eps), beta = b - m*s.
// For the point-MLP bn, bo1 is folded in: beta_o = bo + (bo1 - mo)*s.
// ---------------------------------------------------------------------------
__global__ void prep_bn(const float* g1, const float* b1, const float* m1, const float* v1,
                        const float* g2, const float* b2, const float* m2, const float* v2,
                        const float* g3, const float* b3, const float* m3, const float* v3,
                        const float* go, const float* bo, const float* mo, const float* vo,
                        const float* bo1,
                        float* s1, float* be1, float* s2, float* be2,
                        float* s3, float* be3, float* so, float* beo) {
  int t = threadIdx.x;
  if (t < 256) { float s = g1[t] / sqrtf(v1[t] + EPS); s1[t] = s; be1[t] = b1[t] - m1[t] * s; }
  if (t < 64)  { float s = g2[t] / sqrtf(v2[t] + EPS); s2[t] = s; be2[t] = b2[t] - m2[t] * s; }
  if (t < 32)  { float s = g3[t] / sqrtf(v3[t] + EPS); s3[t] = s; be3[t] = b3[t] - m3[t] * s; }
  if (t < 32)  { float s = go[t] / sqrtf(vo[t] + EPS); so[t] = s; beo[t] = bo[t] + (bo1[t] - mo[t]) * s; }
}

// ---------------------------------------------------------------------------
// weight transform: W[co][ci][27] fp32 -> Wt[t][co][ci] bf16
// ---------------------------------------------------------------------------
__global__ void wtrans(const float* __restrict__ W, uint16_t* __restrict__ Wt,
                       int CO, int CI) {
  int idx = blockIdx.x * 256 + threadIdx.x;
  int total = CO * CI * 27;
  if (idx >= total) return;
  int t = idx / (CO * CI);
  int rem = idx % (CO * CI);
  int co = rem / CI, ci = rem % CI;
  Wt[idx] = f2bf(W[((size_t)co * CI + ci) * 27 + t]);
}

// ---------------------------------------------------------------------------
// fea NCDHW fp32 -> pad0 NDHWC bf16, padded dims [66][66][18][256].
// Register transpose: fully-coalesced fp32 reads (lane-contiguous spatial);
// each thread emits a contiguous 256B bf16 run (full cache lines on write).
// grid = 1024 = b(2) x d(64) x q(4 spatial quarters) x half(2 ci halves).
// ---------------------------------------------------------------------------
__global__ __launch_bounds__(256) void transpose_fea(const float* __restrict__ fea,
                                                     uint16_t* __restrict__ pad0) {
  int tid = threadIdx.x;
  int idx = blockIdx.x;
  int half = idx & 1;
  int q = (idx >> 1) & 3;
  int d = (idx >> 3) & 63;
  int b = idx >> 9;
  int s = q * 256 + tid;               // h*16+w within the d-slice
  int h = s >> 4, w = s & 15;
  const float* src = fea + (size_t)(b * 256 + half * 128) * 65536 + (size_t)d * 1024 + s;
  uint16_t* dst = pad0 + ((size_t)b * 78408 +
                          (size_t)((d + 1) * 1188 + (h + 1) * 18 + (w + 1))) * 256 + half * 128;
#pragma unroll 4
  for (int c8 = 0; c8 < 16; ++c8) {
    uint16_t v[8];
#pragma unroll
    for (int j = 0; j < 8; ++j)
      v[j] = f2bf(src[(size_t)(c8 * 8 + j) * 65536]);
    *(uint4*)&dst[c8 * 8] = *(uint4*)v;
  }
}

// ---------------------------------------------------------------------------
// Implicit-GEMM 3x3x3 conv, NDHWC padded bf16, mfma_f32_16x16x32_bf16,
// fused BN+LeakyReLU.  MTILE=128 (8 h-rows x 16 w), BK=64.
// kw-reuse: A staged as w-extended rows [w'=0..17][mh=0..7][64ci] once per
// (kd,kh,kc) and reused for all 3 kw taps (A staging cut 3x vs per-tap).
// XOR swizzle: LDS[w'][mh][u] holds global 16B-unit (u ^ (w'&7)) so fragment
// ds_read_b128 (lanes vary w') spreads banks; B uses (u ^ (row&7)) as before.
// ---------------------------------------------------------------------------
template <int CI, int CO, int NTILE, int WM, int WN, bool LAST>
__global__ __launch_bounds__(256) void conv_mfma(const uint16_t* __restrict__ padIn,
                                                 const uint16_t* __restrict__ Wt,
                                                 const float* __restrict__ bnS,
                                                 const float* __restrict__ bnB,
                                                 uint16_t* __restrict__ padOut,
                                                 float* __restrict__ x3out) {
  constexpr int MPW = 128 / WM;       // m extent per wave
  constexpr int NPW = NTILE / WN;     // n extent per wave
  constexpr int MSUB = MPW / 16;
  constexpr int NSUB = NPW / 16;
  constexpr int BPASS = NTILE / 32;   // B staging passes (32 rows per pass)
  constexpr int KC = CI / 64;

  __shared__ __align__(16) uint16_t Alds[20 * 8 * 64];  // [w'][mh][ci64], slots 18,19 dummy
  __shared__ __align__(16) uint16_t Blds[NTILE * 64];   // [n][ci64], swizzled

  const int tid = threadIdx.x;
  const int lane = tid & 63;
  const int wv = tid >> 6;
  const int wvm = wv / WN;
  const int wvn = wv % WN;

  const int mt = blockIdx.x;
  const int b = mt >> 9;
  const int r = mt & 511;
  const int d = r >> 3;
  const int h0 = (r & 7) << 3;
  const int n0 = blockIdx.y * NTILE;

  // B staging constants: row = tid>>3 (+32/pass), unit = tid&7, global unit xor'd
  const int subswB = (tid & 7) ^ ((tid >> 3) & 7);
  const int rowB0 = tid >> 3;
  // A staging constants: per wave-pass, lane covers (mh = lane>>3, unit = lane&7)
  const int mhA = lane >> 3;
  const int unA = lane & 7;

  f32x4 acc[MSUB][NSUB] = {};

  const size_t bOffIn = (size_t)b * 78408 * CI;

  for (int dh = 0; dh < 9; ++dh) {
    const int kd = dh / 3, kh = dh % 3;
    const size_t Abase = bOffIn + (size_t)((d + kd) * 1188 + (h0 + kh) * 18) * CI;
    for (int kc = 0; kc < KC; ++kc) {
      for (int kw = 0; kw < 3; ++kw) {
        __syncthreads();  // previous epoch's LDS reads done
        if (kw == 0) {
          // stage A_ext: wave wv stages w'-slots wv*5 .. wv*5+4 (20 incl. 2 dummies)
          const uint16_t* ag = padIn + Abase + kc * 64 + (size_t)mhA * (18 * CI);
#pragma unroll
          for (int p = 0; p < 5; ++p) {
            int wp = wv * 5 + p;
            int gu = unA ^ (wp & 7);
            g2lds16(ag + (size_t)wp * CI + gu * 8, (char*)Alds + wp * 1024);
          }
        }
        {
          const uint16_t* bg = Wt + (size_t)((dh * 3 + kw) * CO + n0) * CI + kc * 64 + subswB * 8;
#pragma unroll
          for (int p = 0; p < BPASS; ++p)
            g2lds16(bg + (size_t)(rowB0 + 32 * p) * CI, (char*)Blds + p * 4096 + wv * 1024);
        }
        __syncthreads();  // staging DMA drained
#pragma unroll
        for (int ks = 0; ks < 2; ++ks) {
          bf16x8 af[MSUB], bfr[NSUB];
#pragma unroll
          for (int mi = 0; mi < MSUB; ++mi) {
            int wq = (lane & 15) + kw;                       // w' for this lane
            int u = (ks * 4 + (lane >> 4)) ^ (wq & 7);
            af[mi] = *(const bf16x8*)&Alds[wq * 512 + (wvm * MSUB + mi) * 64 + u * 8];
          }
#pragma unroll
          for (int ni = 0; ni < NSUB; ++ni) {
            int row = wvn * NPW + ni * 16 + (lane & 15);
            int u = (ks * 4 + (lane >> 4)) ^ (row & 7);
            bfr[ni] = *(const bf16x8*)&Blds[row * 64 + u * 8];
          }
#pragma unroll
          for (int mi = 0; mi < MSUB; ++mi)
#pragma unroll
            for (int ni = 0; ni < NSUB; ++ni)
              acc[mi][ni] = __builtin_amdgcn_mfma_f32_16x16x32_bf16(af[mi], bfr[ni], acc[mi][ni], 0, 0, 0);
        }
      }
    }
  }

  // epilogue: y = x*s + beta, LeakyReLU; C/D layout col=lane&15, row=quad*4+r
  const int col = lane & 15;
  const int quad = lane >> 4;
#pragma unroll
  for (int ni = 0; ni < NSUB; ++ni) {
    const int co = n0 + wvn * NPW + ni * 16 + col;
    const float sv = bnS[co];
    const float bv = bnB[co];
#pragma unroll
    for (int mi = 0; mi < MSUB; ++mi) {
#pragma unroll
      for (int rr = 0; rr < 4; ++rr) {
        int m = wvm * MPW + mi * 16 + quad * 4 + rr;
        float v = acc[mi][ni][rr] * sv + bv;
        v = v > 0.f ? v : SLOPE * v;
        int mh = m >> 4, w = m & 15;
        if (!LAST) {
          size_t o = ((size_t)b * 78408 +
                      (size_t)((d + 1) * 1188 + (h0 + mh + 1) * 18 + (w + 1))) * CO + co;
          padOut[o] = f2bf(v);
        } else {
          size_t o = ((size_t)b * 65536 + (size_t)((d * 64 + h0 + mh) * 16 + w)) * 32 + co;
          x3out[o] = v;
        }
      }
    }
  }
}

// ---------------------------------------------------------------------------
// gather + point MLP, all fp32. One thread per point.
// ---------------------------------------------------------------------------
__global__ __launch_bounds__(256) void gather_mlp(const float* __restrict__ x3,
                                                  const int* __restrict__ gidx,
                                                  const float* __restrict__ xyz,
                                                  const float* __restrict__ Wo1,
                                                  const float* __restrict__ so,
                                                  const float* __restrict__ beo,
                                                  const float* __restrict__ Wo2,
                                                  const float* __restrict__ bo2,
                                                  float* __restrict__ out) {
  __shared__ __align__(16) float w1[35 * 32];
  __shared__ float w2[32 * 3];
  __shared__ float sS[32], sB[32], b2s[3];
  int tid = threadIdx.x;
  for (int i = tid; i < 1120; i += 256) w1[i] = Wo1[i];
  if (tid < 96) w2[tid] = Wo2[tid];
  if (tid < 32) { sS[tid] = so[tid]; sB[tid] = beo[tid]; }
  if (tid < 3) b2s[tid] = bo2[tid];
  __syncthreads();

  int idx = blockIdx.x * 256 + tid;
  if (idx >= 200000) return;
  int b = idx >= 100000 ? 1 : 0;
  int gb = idx * 3;
  int i0 = gidx[gb], i1 = gidx[gb + 1], i2 = gidx[gb + 2];
  const float* pt = x3 + ((size_t)b * 65536 + (size_t)((i0 * 64 + i1) * 16 + i2)) * 32;

  float h[35];
#pragma unroll
  for (int q = 0; q < 8; ++q) {
    float4 v = *(const float4*)(pt + q * 4);
    h[q * 4] = v.x; h[q * 4 + 1] = v.y; h[q * 4 + 2] = v.z; h[q * 4 + 3] = v.w;
  }
  h[32] = xyz[gb]; h[33] = xyz[gb + 1]; h[34] = xyz[gb + 2];

  float a[32];
#pragma unroll
  for (int j = 0; j < 32; ++j) a[j] = 0.f;
#pragma unroll
  for (int k = 0; k < 35; ++k) {
    float hk = h[k];
    const float4* wr = (const float4*)(w1 + k * 32);
#pragma unroll
    for (int q = 0; q < 8; ++q) {
      float4 wv = wr[q];
      a[q * 4 + 0] += hk * wv.x;
      a[q * 4 + 1] += hk * wv.y;
      a[q * 4 + 2] += hk * wv.z;
      a[q * 4 + 3] += hk * wv.w;
    }
  }
  float o0 = b2s[0], o1 = b2s[1], o2 = b2s[2];
#pragma unroll
  for (int j = 0; j < 32; ++j) {
    float y = a[j] * sS[j] + sB[j];
    y = y > 0.f ? y : 0.f;
    o0 += y * w2[j * 3 + 0];
    o1 += y * w2[j * 3 + 1];
    o2 += y * w2[j * 3 + 2];
  }
  out[gb] = o0; out[gb + 1] = o1; out[gb + 2] = o2;
}

// ---------------------------------------------------------------------------
// workspace layout (bytes):
//   pad0: 0            .. 80,289,792   (2*78408*256*2)
//         [after conv1: pad2 @0 (20,072,448), x3 @20,072,448 (16,777,216)]
//   pad1: 80,289,792   .. 160,579,584
//   Wt1 : 160,579,584  (3,538,944)
//   Wt2 : 164,118,528  (884,736)
//   Wt3 : 165,003,264  (110,592)
//   bn  : 165,113,856  (8 slots x 1024B)
// total ~165.2 MB.  (A-staging dummy slots may read <=512B past a pad
// buffer's end — always into the next ws region, never past ws.)
// ---------------------------------------------------------------------------
extern "C" void kernel_launch(void* const* d_in, const int* in_sizes, int n_in,
                              void* d_out, int out_size, void* d_ws, size_t ws_size,
                              hipStream_t stream) {
  (void)in_sizes; (void)n_in; (void)out_size;
  if (ws_size < 165130000) return;  // workspace too small — bail loudly (absmax will fail)

  const float* fea = (const float*)d_in[0];
  const int*   gidx = (const int*)d_in[1];
  const float* xyz = (const float*)d_in[2];
  const float* W1 = (const float*)d_in[3];
  const float* g1 = (const float*)d_in[4];
  const float* b1 = (const float*)d_in[5];
  const float* m1 = (const float*)d_in[6];
  const float* v1 = (const float*)d_in[7];
  const float* W2 = (const float*)d_in[8];
  const float* g2 = (const float*)d_in[9];
  const float* b2 = (const float*)d_in[10];
  const float* m2 = (const float*)d_in[11];
  const float* v2 = (const float*)d_in[12];
  const float* W3 = (const float*)d_in[13];
  const float* g3 = (const float*)d_in[14];
  const float* b3 = (const float*)d_in[15];
  const float* m3 = (const float*)d_in[16];
  const float* v3 = (const float*)d_in[17];
  const float* Wo1 = (const float*)d_in[18];
  const float* bo1 = (const float*)d_in[19];
  const float* go = (const float*)d_in[20];
  const float* bo = (const float*)d_in[21];
  const float* mo = (const float*)d_in[22];
  const float* vo = (const float*)d_in[23];
  const float* Wo2 = (const float*)d_in[24];
  const float* bo2 = (const float*)d_in[25];

  char* ws = (char*)d_ws;
  uint16_t* pad0 = (uint16_t*)(ws);
  uint16_t* pad1 = (uint16_t*)(ws + 80289792);
  uint16_t* Wt1 = (uint16_t*)(ws + 160579584);
  uint16_t* Wt2 = (uint16_t*)(ws + 164118528);
  uint16_t* Wt3 = (uint16_t*)(ws + 165003264);
  float* s1  = (float*)(ws + 165113856 + 0 * 1024);
  float* be1 = (float*)(ws + 165113856 + 1 * 1024);
  float* s2  = (float*)(ws + 165113856 + 2 * 1024);
  float* be2 = (float*)(ws + 165113856 + 3 * 1024);
  float* s3  = (float*)(ws + 165113856 + 4 * 1024);
  float* be3 = (float*)(ws + 165113856 + 5 * 1024);
  float* so  = (float*)(ws + 165113856 + 6 * 1024);
  float* beo = (float*)(ws + 165113856 + 7 * 1024);
  // aliases into pad0's region (pad0 is dead after conv1)
  uint16_t* pad2 = (uint16_t*)(ws);
  float* x3 = (float*)(ws + 20072448);

  // zero halos of pad0+pad1 (contiguous)
  hipMemsetAsync(ws, 0, 160579584, stream);

  prep_bn<<<1, 256, 0, stream>>>(g1, b1, m1, v1, g2, b2, m2, v2, g3, b3, m3, v3,
                                 go, bo, mo, vo, bo1, s1, be1, s2, be2, s3, be3, so, beo);
  wtrans<<<6912, 256, 0, stream>>>(W1, Wt1, 256, 256);
  wtrans<<<1728, 256, 0, stream>>>(W2, Wt2, 64, 256);
  wtrans<<<216, 256, 0, stream>>>(W3, Wt3, 32, 64);
  transpose_fea<<<1024, 256, 0, stream>>>(fea, pad0);

  conv_mfma<256, 256, 128, 2, 2, false>
      <<<dim3(1024, 2), 256, 0, stream>>>(pad0, Wt1, s1, be1, pad1, nullptr);

  hipMemsetAsync(pad2, 0, 20072448, stream);  // pad2 halo (pad0 now dead; stream-ordered)

  conv_mfma<256, 64, 64, 2, 2, false>
      <<<dim3(1024, 1), 256, 0, stream>>>(pad1, Wt2, s2, be2, pad2, nullptr);

  conv_mfma<64, 32, 32, 4, 1, true>
      <<<dim3(1024, 1), 256, 0, stream>>>(pad2, Wt3, s3, be3, nullptr, x3);

  gather_mlp<<<782, 256, 0, stream>>>(x3, gidx, xyz, Wo1, so, beo, Wo2, bo2, (float*)d_out);
}

// Round 3
// 1042.380 us; speedup vs baseline: 1.0502x; 1.0034x over previous
//
#include <hip/hip_runtime.h>
#include <stdint.h>

#define EPS 1e-5f
#define SLOPE 0.01f

typedef short bf16x8 __attribute__((ext_vector_type(8)));
typedef float f32x4 __attribute__((ext_vector_type(4)));

// round-to-nearest-even fp32 -> bf16
__device__ __forceinline__ uint16_t f2bf(float x) {
  union { float f; uint32_t u; } v; v.f = x;
  return (uint16_t)((v.u + 0x7fffu + ((v.u >> 16) & 1u)) >> 16);
}

// async global->LDS, 16B per lane; LDS dest = wave-uniform base + lane*16
__device__ __forceinline__ void g2lds16(const void* g, void* l) {
  __builtin_amdgcn_global_load_lds(
      (const __attribute__((address_space(1))) void*)g,
      (__attribute__((address_space(3))) void*)l, 16, 0, 0);
}

// ---------------------------------------------------------------------------
// prep: bn scale/bias folding.  s = g/sqrt(v+eps), beta = b - m*s.
// For the point-MLP bn, bo1 is folded in: beta_o = bo + (bo1 - mo)*s.
// ---------------------------------------------------------------------------
__global__ void prep_bn(const float* g1, const float* b1, const float* m1, const float* v1,
                        const float* g2, const float* b2, const float* m2, const float* v2,
                        const float* g3, const float* b3, const float* m3, const float* v3,
                        const float* go, const float* bo, const float* mo, const float* vo,
                        const float* bo1,
                        float* s1, float* be1, float* s2, float* be2,
                        float* s3, float* be3, float* so, float* beo) {
  int t = threadIdx.x;
  if (t < 256) { float s = g1[t] / sqrtf(v1[t] + EPS); s1[t] = s; be1[t] = b1[t] - m1[t] * s; }
  if (t < 64)  { float s = g2[t] / sqrtf(v2[t] + EPS); s2[t] = s; be2[t] = b2[t] - m2[t] * s; }
  if (t < 32)  { float s = g3[t] / sqrtf(v3[t] + EPS); s3[t] = s; be3[t] = b3[t] - m3[t] * s; }
  if (t < 32)  { float s = go[t] / sqrtf(vo[t] + EPS); so[t] = s; beo[t] = bo[t] + (bo1[t] - mo[t]) * s; }
}

// ---------------------------------------------------------------------------
// weight transform: W[co][ci][27] fp32 -> Wt[t][co][ci] bf16
// ---------------------------------------------------------------------------
__global__ void wtrans(const float* __restrict__ W, uint16_t* __restrict__ Wt,
                       int CO, int CI) {
  int idx = blockIdx.x * 256 + threadIdx.x;
  int total = CO * CI * 27;
  if (idx >= total) return;
  int t = idx / (CO * CI);
  int rem = idx % (CO * CI);
  int co = rem / CI, ci = rem % CI;
  Wt[idx] = f2bf(W[((size_t)co * CI + ci) * 27 + t]);
}

// ---------------------------------------------------------------------------
// fea NCDHW fp32 -> pad0 NDHWC bf16, padded dims [66][66][18][256].
// Register transpose: fully-coalesced fp32 reads (lane-contiguous spatial);
// each thread emits a contiguous 256B bf16 run (full cache lines on write).
// ---------------------------------------------------------------------------
__global__ __launch_bounds__(256) void transpose_fea(const float* __restrict__ fea,
                                                     uint16_t* __restrict__ pad0) {
  int tid = threadIdx.x;
  int idx = blockIdx.x;
  int half = idx & 1;
  int q = (idx >> 1) & 3;
  int d = (idx >> 3) & 63;
  int b = idx >> 9;
  int s = q * 256 + tid;               // h*16+w within the d-slice
  int h = s >> 4, w = s & 15;
  const float* src = fea + (size_t)(b * 256 + half * 128) * 65536 + (size_t)d * 1024 + s;
  uint16_t* dst = pad0 + ((size_t)b * 78408 +
                          (size_t)((d + 1) * 1188 + (h + 1) * 18 + (w + 1))) * 256 + half * 128;
#pragma unroll 4
  for (int c8 = 0; c8 < 16; ++c8) {
    uint16_t v[8];
#pragma unroll
    for (int j = 0; j < 8; ++j)
      v[j] = f2bf(src[(size_t)(c8 * 8 + j) * 65536]);
    *(uint4*)&dst[c8 * 8] = *(uint4*)v;
  }
}

// ---------------------------------------------------------------------------
// Implicit-GEMM 3x3x3 conv, NDHWC padded bf16, mfma_f32_16x16x32_bf16,
// fused BN+LeakyReLU.  MTILE=MH*16 (MH h-rows x 16 w), NTILE=CO, BK=64.
// kw-reuse: A staged as w-extended rows [w'=0..17][mh][64ci] once per
// (kd,kh,kc), reused for kw=0,1,2.  Per-wave tile (MTILE/WM) x (NTILE/WN);
// LDS-read economics = Mw*Nw/(Mw+Nw) FLOP/byte — maximize per-wave area.
// XOR swizzle: A unit stored at (u ^ (w'&7)); B at (u ^ (row&7)).
// ---------------------------------------------------------------------------
template <int CI, int CO, int MH, int WM, int WN, bool LAST>
__global__ __launch_bounds__(256, 2) void conv_mfma(const uint16_t* __restrict__ padIn,
                                                    const uint16_t* __restrict__ Wt,
                                                    const float* __restrict__ bnS,
                                                    const float* __restrict__ bnB,
                                                    uint16_t* __restrict__ padOut,
                                                    float* __restrict__ x3out) {
  constexpr int NTILE = CO;
  constexpr int MTILE = MH * 16;
  constexpr int MPW = MTILE / WM;
  constexpr int NPW = NTILE / WN;
  constexpr int MSUB = MPW / 16;
  constexpr int NSUB = NPW / 16;
  constexpr int BPASS = NTILE / 32;
  constexpr int KC = CI / 64;
  constexpr int HB = 64 / MH;
  constexpr int HALF = MH / 8;
  constexpr int ROWSTR = 18 * CI;   // padded w-row stride (elements)

  __shared__ __align__(16) uint16_t Alds[20 * MH * 64];  // [w'][mh][ci64]; w' 18,19 dummy
  __shared__ __align__(16) uint16_t Blds[NTILE * 64];    // [n][ci64]

  const int tid = threadIdx.x;
  const int lane = tid & 63;
  const int wv = tid >> 6;
  const int wvm = wv / WN;
  const int wvn = wv % WN;

  const int mt = blockIdx.x;
  const int b = mt / (64 * HB);
  const int r = mt % (64 * HB);
  const int d = r / HB;
  const int h0 = (r % HB) * MH;

  // B staging constants
  const int subswB = (tid & 7) ^ ((tid >> 3) & 7);
  const int rowB0 = tid >> 3;

  f32x4 acc[MSUB][NSUB] = {};

  const size_t bOffIn = (size_t)b * 78408 * CI;

  for (int dh = 0; dh < 9; ++dh) {
    const int kd = dh / 3, kh = dh % 3;
    const size_t Abase = bOffIn + (size_t)((d + kd) * 1188 + (h0 + kh) * 18) * CI;
    for (int kc = 0; kc < KC; ++kc) {
      for (int kw = 0; kw < 3; ++kw) {
        __syncthreads();  // previous epoch's LDS reads done
        if (kw == 0) {
          // stage A_ext: wave wv covers w'-slots wv*5..wv*5+4 (20 incl. dummies),
          // each slot = HALF instrs of (8 mh-rows x 128B), lanes: mh=lane>>3, unit=lane&7
          const uint16_t* agBase = padIn + Abase + kc * 64 + (size_t)(lane >> 3) * ROWSTR;
#pragma unroll
          for (int p = 0; p < 5; ++p) {
            int wp = wv * 5 + p;
            int gu = (lane & 7) ^ (wp & 7);
#pragma unroll
            for (int hf = 0; hf < HALF; ++hf)
              g2lds16(agBase + (size_t)(hf * 8) * ROWSTR + wp * CI + gu * 8,
                      (char*)Alds + wp * (MH * 128) + hf * 1024);
          }
        }
        {
          const uint16_t* bg = Wt + (size_t)((dh * 3 + kw) * CO) * CI + kc * 64 + subswB * 8;
#pragma unroll
          for (int p = 0; p < BPASS; ++p)
            g2lds16(bg + (size_t)(rowB0 + 32 * p) * CI, (char*)Blds + p * 4096 + wv * 1024);
        }
        __syncthreads();  // staging DMA drained
#pragma unroll
        for (int ks = 0; ks < 2; ++ks) {
          bf16x8 af[MSUB], bfr[NSUB];
#pragma unroll
          for (int mi = 0; mi < MSUB; ++mi) {
            int wq = (lane & 15) + kw;
            int u = (ks * 4 + (lane >> 4)) ^ (wq & 7);
            int mhIdx = wvm * MSUB + mi;
            af[mi] = *(const bf16x8*)&Alds[wq * (MH * 64) + mhIdx * 64 + u * 8];
          }
#pragma unroll
          for (int ni = 0; ni < NSUB; ++ni) {
            int row = wvn * NPW + ni * 16 + (lane & 15);
            int u = (ks * 4 + (lane >> 4)) ^ (row & 7);
            bfr[ni] = *(const bf16x8*)&Blds[row * 64 + u * 8];
          }
#pragma unroll
          for (int mi = 0; mi < MSUB; ++mi)
#pragma unroll
            for (int ni = 0; ni < NSUB; ++ni)
              acc[mi][ni] = __builtin_amdgcn_mfma_f32_16x16x32_bf16(af[mi], bfr[ni], acc[mi][ni], 0, 0, 0);
        }
      }
    }
  }

  // epilogue: y = x*s + beta, LeakyReLU; C/D layout col=lane&15, row=quad*4+r
  const int col = lane & 15;
  const int quad = lane >> 4;
#pragma unroll
  for (int ni = 0; ni < NSUB; ++ni) {
    const int co = wvn * NPW + ni * 16 + col;
    const float sv = bnS[co];
    const float bv = bnB[co];
#pragma unroll
    for (int mi = 0; mi < MSUB; ++mi) {
#pragma unroll
      for (int rr = 0; rr < 4; ++rr) {
        int m = wvm * MPW + mi * 16 + quad * 4 + rr;
        float v = acc[mi][ni][rr] * sv + bv;
        v = v > 0.f ? v : SLOPE * v;
        int mh = m >> 4, w = m & 15;
        if (!LAST) {
          size_t o = ((size_t)b * 78408 +
                      (size_t)((d + 1) * 1188 + (h0 + mh + 1) * 18 + (w + 1))) * CO + co;
          padOut[o] = f2bf(v);
        } else {
          size_t o = ((size_t)b * 65536 + (size_t)((d * 64 + h0 + mh) * 16 + w)) * 32 + co;
          x3out[o] = v;
        }
      }
    }
  }
}

// ---------------------------------------------------------------------------
// gather + point MLP, all fp32. One thread per point.
// ---------------------------------------------------------------------------
__global__ __launch_bounds__(256) void gather_mlp(const float* __restrict__ x3,
                                                  const int* __restrict__ gidx,
                                                  const float* __restrict__ xyz,
                                                  const float* __restrict__ Wo1,
                                                  const float* __restrict__ so,
                                                  const float* __restrict__ beo,
                                                  const float* __restrict__ Wo2,
                                                  const float* __restrict__ bo2,
                                                  float* __restrict__ out) {
  __shared__ __align__(16) float w1[35 * 32];
  __shared__ float w2[32 * 3];
  __shared__ float sS[32], sB[32], b2s[3];
  int tid = threadIdx.x;
  for (int i = tid; i < 1120; i += 256) w1[i] = Wo1[i];
  if (tid < 96) w2[tid] = Wo2[tid];
  if (tid < 32) { sS[tid] = so[tid]; sB[tid] = beo[tid]; }
  if (tid < 3) b2s[tid] = bo2[tid];
  __syncthreads();

  int idx = blockIdx.x * 256 + tid;
  if (idx >= 200000) return;
  int b = idx >= 100000 ? 1 : 0;
  int gb = idx * 3;
  int i0 = gidx[gb], i1 = gidx[gb + 1], i2 = gidx[gb + 2];
  const float* pt = x3 + ((size_t)b * 65536 + (size_t)((i0 * 64 + i1) * 16 + i2)) * 32;

  float h[35];
#pragma unroll
  for (int q = 0; q < 8; ++q) {
    float4 v = *(const float4*)(pt + q * 4);
    h[q * 4] = v.x; h[q * 4 + 1] = v.y; h[q * 4 + 2] = v.z; h[q * 4 + 3] = v.w;
  }
  h[32] = xyz[gb]; h[33] = xyz[gb + 1]; h[34] = xyz[gb + 2];

  float a[32];
#pragma unroll
  for (int j = 0; j < 32; ++j) a[j] = 0.f;
#pragma unroll
  for (int k = 0; k < 35; ++k) {
    float hk = h[k];
    const float4* wr = (const float4*)(w1 + k * 32);
#pragma unroll
    for (int q = 0; q < 8; ++q) {
      float4 wv = wr[q];
      a[q * 4 + 0] += hk * wv.x;
      a[q * 4 + 1] += hk * wv.y;
      a[q * 4 + 2] += hk * wv.z;
      a[q * 4 + 3] += hk * wv.w;
    }
  }
  float o0 = b2s[0], o1 = b2s[1], o2 = b2s[2];
#pragma unroll
  for (int j = 0; j < 32; ++j) {
    float y = a[j] * sS[j] + sB[j];
    y = y > 0.f ? y : 0.f;
    o0 += y * w2[j * 3 + 0];
    o1 += y * w2[j * 3 + 1];
    o2 += y * w2[j * 3 + 2];
  }
  out[gb] = o0; out[gb + 1] = o1; out[gb + 2] = o2;
}

// ---------------------------------------------------------------------------
// workspace layout (bytes):
//   pad0: 0            .. 80,289,792   (2*78408*256*2)
//         [after conv1: pad2 @0 (20,072,448), x3 @20,072,448 (16,777,216)]
//   pad1: 80,289,792   .. 160,579,584
//   Wt1 : 160,579,584  (3,538,944)
//   Wt2 : 164,118,528  (884,736)
//   Wt3 : 165,003,264  (110,592)
//   bn  : 165,113,856  (8 slots x 1024B)
// total ~165.2 MB.  (A-staging dummy slots may read <=1KB past a pad
// buffer's end — always into the next ws region, never past ws.)
// ---------------------------------------------------------------------------
extern "C" void kernel_launch(void* const* d_in, const int* in_sizes, int n_in,
                              void* d_out, int out_size, void* d_ws, size_t ws_size,
                              hipStream_t stream) {
  (void)in_sizes; (void)n_in; (void)out_size;
  if (ws_size < 165130000) return;  // workspace too small — bail loudly (absmax will fail)

  const float* fea = (const float*)d_in[0];
  const int*   gidx = (const int*)d_in[1];
  const float* xyz = (const float*)d_in[2];
  const float* W1 = (const float*)d_in[3];
  const float* g1 = (const float*)d_in[4];
  const float* b1 = (const float*)d_in[5];
  const float* m1 = (const float*)d_in[6];
  const float* v1 = (const float*)d_in[7];
  const float* W2 = (const float*)d_in[8];
  const float* g2 = (const float*)d_in[9];
  const float* b2 = (const float*)d_in[10];
  const float* m2 = (const float*)d_in[11];
  const float* v2 = (const float*)d_in[12];
  const float* W3 = (const float*)d_in[13];
  const float* g3 = (const float*)d_in[14];
  const float* b3 = (const float*)d_in[15];
  const float* m3 = (const float*)d_in[16];
  const float* v3 = (const float*)d_in[17];
  const float* Wo1 = (const float*)d_in[18];
  const float* bo1 = (const float*)d_in[19];
  const float* go = (const float*)d_in[20];
  const float* bo = (const float*)d_in[21];
  const float* mo = (const float*)d_in[22];
  const float* vo = (const float*)d_in[23];
  const float* Wo2 = (const float*)d_in[24];
  const float* bo2 = (const float*)d_in[25];

  char* ws = (char*)d_ws;
  uint16_t* pad0 = (uint16_t*)(ws);
  uint16_t* pad1 = (uint16_t*)(ws + 80289792);
  uint16_t* Wt1 = (uint16_t*)(ws + 160579584);
  uint16_t* Wt2 = (uint16_t*)(ws + 164118528);
  uint16_t* Wt3 = (uint16_t*)(ws + 165003264);
  float* s1  = (float*)(ws + 165113856 + 0 * 1024);
  float* be1 = (float*)(ws + 165113856 + 1 * 1024);
  float* s2  = (float*)(ws + 165113856 + 2 * 1024);
  float* be2 = (float*)(ws + 165113856 + 3 * 1024);
  float* s3  = (float*)(ws + 165113856 + 4 * 1024);
  float* be3 = (float*)(ws + 165113856 + 5 * 1024);
  float* so  = (float*)(ws + 165113856 + 6 * 1024);
  float* beo = (float*)(ws + 165113856 + 7 * 1024);
  // aliases into pad0's region (pad0 is dead after conv1)
  uint16_t* pad2 = (uint16_t*)(ws);
  float* x3 = (float*)(ws + 20072448);

  // zero halos of pad0+pad1 (contiguous)
  hipMemsetAsync(ws, 0, 160579584, stream);

  prep_bn<<<1, 256, 0, stream>>>(g1, b1, m1, v1, g2, b2, m2, v2, g3, b3, m3, v3,
                                 go, bo, mo, vo, bo1, s1, be1, s2, be2, s3, be3, so, beo);
  wtrans<<<6912, 256, 0, stream>>>(W1, Wt1, 256, 256);
  wtrans<<<1728, 256, 0, stream>>>(W2, Wt2, 64, 256);
  wtrans<<<216, 256, 0, stream>>>(W3, Wt3, 32, 64);
  transpose_fea<<<1024, 256, 0, stream>>>(fea, pad0);

  // conv1: CI=256, CO=256, MH=8 (MTILE=128), waves 2x2, per-wave 64x128
  conv_mfma<256, 256, 8, 2, 2, false>
      <<<1024, 256, 0, stream>>>(pad0, Wt1, s1, be1, pad1, nullptr);

  hipMemsetAsync(pad2, 0, 20072448, stream);  // pad2 halo (pad0 now dead; stream-ordered)

  // conv2: CI=256, CO=64, MH=16 (MTILE=256), waves 4x1, per-wave 64x64
  conv_mfma<256, 64, 16, 4, 1, false>
      <<<512, 256, 0, stream>>>(pad1, Wt2, s2, be2, pad2, nullptr);

  // conv3: CI=64, CO=32, MH=16 (MTILE=256), waves 4x1, per-wave 64x32
  conv_mfma<64, 32, 16, 4, 1, true>
      <<<512, 256, 0, stream>>>(pad2, Wt3, s3, be3, nullptr, x3);

  gather_mlp<<<782, 256, 0, stream>>>(x3, gidx, xyz, Wo1, so, beo, Wo2, bo2, (float*)d_out);
}